// Round 4
// baseline (7786.729 us; speedup 1.0000x reference)
//
#include <hip/hip_runtime.h>
#include <hip/hip_bf16.h>
#include <float.h>
#include <math.h>

#define NB 4
#define NN 8192
#define FF 64
#define MM 2048
#define KK 32
#define HH 64

#define FT 512          // fps threads (8 waves)
#define PPT 16          // points per thread (FT*PPT == NN)
#define NG 128          // groups of 64 points

// 3-wide DPP argmax step: carries (value, orig idx, slot idx); tie -> lower oi.
// identities: v=-inf, oi=INT_MAX, si=0 (never selected).
#define DPP3_STEP(bv, boi, bsi, ctrl, rmask)                                    \
    {                                                                           \
        int _v  = __builtin_amdgcn_update_dpp((int)0xff800000,                  \
                      __float_as_int(bv), (ctrl), (rmask), 0xf, false);         \
        int _oi = __builtin_amdgcn_update_dpp((int)0x7fffffff,                  \
                      (boi), (ctrl), (rmask), 0xf, false);                      \
        int _si = __builtin_amdgcn_update_dpp(0, (bsi), (ctrl), (rmask), 0xf, false); \
        float _vf = __int_as_float(_v);                                         \
        if (_vf > (bv) || (_vf == (bv) && _oi < (boi)))                         \
            { (bv) = _vf; (boi) = _oi; (bsi) = _si; }                           \
    }
#define DPP3_REDUCE(bv, boi, bsi)            \
    DPP3_STEP(bv, boi, bsi, 0x111, 0xf)      \
    DPP3_STEP(bv, boi, bsi, 0x112, 0xf)      \
    DPP3_STEP(bv, boi, bsi, 0x114, 0xf)      \
    DPP3_STEP(bv, boi, bsi, 0x118, 0xf)      \
    DPP3_STEP(bv, boi, bsi, 0x142, 0xa)      \
    DPP3_STEP(bv, boi, bsi, 0x143, 0xc)

#define DPP_FADD(v, ctrl, rmask)                                                \
    { int _t = __builtin_amdgcn_update_dpp(0, __float_as_int(v), (ctrl),        \
                   (rmask), 0xf, false);                                        \
      (v) = __fadd_rn((v), __int_as_float(_t)); }
#define DPP_FMAX(v, ctrl, rmask)                                                \
    { int _t = __builtin_amdgcn_update_dpp((int)0xff800000, __float_as_int(v),  \
                   (ctrl), (rmask), 0xf, false);                                \
      (v) = fmaxf((v), __int_as_float(_t)); }
#define DPP_SUM6(v)  DPP_FADD(v,0x111,0xf) DPP_FADD(v,0x112,0xf) DPP_FADD(v,0x114,0xf) \
                     DPP_FADD(v,0x118,0xf) DPP_FADD(v,0x142,0xa) DPP_FADD(v,0x143,0xc)
#define DPP_MAX6(v)  DPP_FMAX(v,0x111,0xf) DPP_FMAX(v,0x112,0xf) DPP_FMAX(v,0x114,0xf) \
                     DPP_FMAX(v,0x118,0xf) DPP_FMAX(v,0x142,0xa) DPP_FMAX(v,0x143,0xc)

__device__ __forceinline__ int spread3(int v) {
    return (v & 1) | ((v & 2) << 2) | ((v & 4) << 4);
}
__device__ __forceinline__ float readlane_f(float v, int l) {
    return __int_as_float(__builtin_amdgcn_readlane(__float_as_int(v), l));
}

// ---------------- Kernel 1: exact FPS with group pruning ----------------
__global__ __launch_bounds__(FT) void fps_kernel(
    const float* __restrict__ pos,
    int* __restrict__ samp,
    float* __restrict__ centers_out,
    float* __restrict__ batch_out)
{
    __shared__ float xs[NN], ys[NN], zs[NN];   // Morton-sorted SoA (96 KB)
    __shared__ int   oidxL[NN];                // sorted slot -> original idx (32 KB)
    __shared__ float2 gwin_v[2][NG];           // per-group (maxdist, oi-bits), parity
    __shared__ int    gwin_s[2][NG];           // per-group winner slot, parity
    __shared__ float cgx[NG], cgy[NG], cgz[NG], cr[NG];
    __shared__ int hist[512], off[512];

    const int b = blockIdx.x;
    const float* pb = pos + (size_t)b * NN * 3;
    const int tid = threadIdx.x;
    const int w   = tid >> 6;
    const int lane = tid & 63;

    // ---- setup: load, morton, counting sort ----
    float px[PPT], py[PPT], pz[PPT];
    int   mt[PPT];
    hist[tid] = 0;
    __syncthreads();
#pragma unroll
    for (int i = 0; i < PPT; ++i) {
        const int j = tid + i * FT;
        px[i] = pb[j * 3 + 0];
        py[i] = pb[j * 3 + 1];
        pz[i] = pb[j * 3 + 2];
        int cx = (int)(px[i] * 8.0f), cy = (int)(py[i] * 8.0f), cz = (int)(pz[i] * 8.0f);
        cx = min(max(cx, 0), 7); cy = min(max(cy, 0), 7); cz = min(max(cz, 0), 7);
        mt[i] = spread3(cx) | (spread3(cy) << 1) | (spread3(cz) << 2);
        atomicAdd(&hist[mt[i]], 1);
    }
    for (int j = tid; j < MM; j += FT) batch_out[b * MM + j] = (float)b;
    __syncthreads();
    for (int d = 1; d < 512; d <<= 1) {
        int v = hist[tid] + ((tid >= d) ? hist[tid - d] : 0);
        __syncthreads();
        hist[tid] = v;
        __syncthreads();
    }
    off[tid] = (tid == 0) ? 0 : hist[tid - 1];
    __syncthreads();
#pragma unroll
    for (int i = 0; i < PPT; ++i) {
        const int slot = atomicAdd(&off[mt[i]], 1);
        xs[slot] = px[i]; ys[slot] = py[i]; zs[slot] = pz[i];
        oidxL[slot] = tid + i * FT;
    }
    __syncthreads();

    // ---- owners load dist/oi; group metadata (centroid, radius) ----
    float dist_r[PPT];
    int   oi_r[PPT];
#pragma unroll
    for (int i = 0; i < PPT; ++i) {
        const int g = w + (i << 3);
        const int ss = (g << 6) + lane;
        dist_r[i] = INFINITY;
        oi_r[i] = oidxL[ss];
        float x = xs[ss], y = ys[ss], z = zs[ss];
        float sx = x, sy = y, sz = z;
        DPP_SUM6(sx) DPP_SUM6(sy) DPP_SUM6(sz)
        const float gx = readlane_f(sx, 63) * (1.0f / 64.0f);
        const float gy = readlane_f(sy, 63) * (1.0f / 64.0f);
        const float gz = readlane_f(sz, 63) * (1.0f / 64.0f);
        float dx = x - gx, dy = y - gy, dz = z - gz;
        float d2 = dx * dx + dy * dy + dz * dz;
        DPP_MAX6(d2)
        const float r2 = readlane_f(d2, 63);
        if (lane == 0) {
            cgx[g] = gx; cgy[g] = gy; cgz[g] = gz;
            cr[g] = sqrtf(r2) * 1.00005f + 1e-7f;   // conservative upper bound
        }
    }
    if (tid < NG) {   // buffer 1 = "previous" at step 0: only .x (inf) is read
        gwin_v[1][tid] = make_float2(INFINITY, __int_as_float(0x7fffffff));
        gwin_s[1][tid] = 0;
    }
    __syncthreads();

    int   cur = 0;
    float lx = pb[0], ly = pb[1], lz = pb[2];

    for (int s = 0; s < MM; ++s) {
        if (tid == 0) {
            samp[b * MM + s] = cur;
            centers_out[((size_t)b * MM + s) * 3 + 0] = lx;
            centers_out[((size_t)b * MM + s) * 3 + 1] = ly;
            centers_out[((size_t)b * MM + s) * 3 + 2] = lz;
        }
        if (s == MM - 1) break;

        const int par = s & 1, prev = par ^ 1;

        // ---- prune test: lane i (<16) handles group w + 8i ----
        bool flag = false;
        if (lane < 16) {
            const int g = w + (lane << 3);
            const float dx = cgx[g] - lx, dy = cgy[g] - ly, dz = cgz[g] - lz;
            const float d2c = dx * dx + dy * dy + dz * dz;
            const float t = __fsub_rn(__fmul_rn(sqrtf(d2c), 0.99999f), cr[g]);
            const float gm = gwin_v[prev][g].x;
            const bool skip = (t > 0.0f) &&
                              (__fmul_rn(t, t) >= __fmul_rn(gm, 1.00004f));
            flag = !skip;
            if (skip) {   // winner unchanged: carry forward
                gwin_v[par][g] = gwin_v[prev][g];
                gwin_s[par][g] = gwin_s[prev][g];
            }
        }
        const unsigned long long mask = __ballot(flag);

        // ---- update flagged groups (wave-uniform branches) ----
#pragma unroll
        for (int i = 0; i < 16; ++i) {
            if ((mask >> i) & 1ull) {
                const int g = w + (i << 3);
                const int ss = (g << 6) + lane;
                // exact ref arithmetic: ((dx*dx + dy*dy) + dz*dz), no FMA
                const float dx = __fsub_rn(xs[ss], lx);
                const float dy = __fsub_rn(ys[ss], ly);
                const float dz = __fsub_rn(zs[ss], lz);
                const float d2 = __fadd_rn(__fadd_rn(__fmul_rn(dx, dx),
                                                     __fmul_rn(dy, dy)),
                                           __fmul_rn(dz, dz));
                const float nd = fminf(dist_r[i], d2);
                dist_r[i] = nd;
                float bv = nd; int boi = oi_r[i]; int bsi = ss;
                DPP3_REDUCE(bv, boi, bsi)
                if (lane == 63) {
                    gwin_v[par][g] = make_float2(bv, __int_as_float(boi));
                    gwin_s[par][g] = bsi;
                }
            }
        }
        __syncthreads();

        // ---- block argmax over 128 cached group winners (all waves, redundant) ----
        const float2 e0 = gwin_v[par][lane];
        const float2 e1 = gwin_v[par][64 + lane];
        const int   t0 = gwin_s[par][lane];
        const int   t1 = gwin_s[par][64 + lane];
        float bv = e0.x; int boi = __float_as_int(e0.y); int bsi = t0;
        {
            const float v1 = e1.x; const int o1 = __float_as_int(e1.y);
            if (v1 > bv || (v1 == bv && o1 < boi)) { bv = v1; boi = o1; bsi = t1; }
        }
        DPP3_REDUCE(bv, boi, bsi)
        cur = __builtin_amdgcn_readlane(boi, 63);
        const int csi = __builtin_amdgcn_readlane(bsi, 63);
        lx = xs[csi]; ly = ys[csi]; lz = zs[csi];
    }
}

// ---------------- Kernel 2: radius-KNN, one wave per center ----------------
#define CAP 256
__global__ __launch_bounds__(256) void knn_kernel(
    const float* __restrict__ pos,
    const int* __restrict__ samp,
    int* __restrict__ nbr,
    int* __restrict__ cntbuf)
{
    const int wave = threadIdx.x >> 6;
    const int lane = threadIdx.x & 63;
    const int c = blockIdx.x * 4 + wave;
    const int b = c >> 11;
    const float* pb = pos + (size_t)b * NN * 3;

    __shared__ float sd2[4][CAP];
    __shared__ int   sid[4][CAP];

    const int ctr = samp[c];
    const float cx = pb[ctr * 3 + 0];
    const float cy = pb[ctr * 3 + 1];
    const float cz = pb[ctr * 3 + 2];
    const float R2 = (float)(0.1 * 0.1);

    int cnt = 0;
    for (int r = 0; r < NN / 64; ++r) {
        const int g = r * 64 + lane;
        float dx = __fsub_rn(cx, pb[g * 3 + 0]);
        float dy = __fsub_rn(cy, pb[g * 3 + 1]);
        float dz = __fsub_rn(cz, pb[g * 3 + 2]);
        float d2 = __fadd_rn(__fadd_rn(__fmul_rn(dx, dx), __fmul_rn(dy, dy)),
                             __fmul_rn(dz, dz));
        const bool pred = (d2 <= R2);
        const unsigned long long mask = __ballot(pred);
        const int before = __popcll(mask & ((1ull << lane) - 1ull));
        if (pred) {
            const int slot = cnt + before;
            if (slot < CAP) { sd2[wave][slot] = d2; sid[wave][slot] = g; }
        }
        cnt += __popcll(mask);
    }
    if (cnt > CAP) cnt = CAP;
    __syncthreads();

    for (int ci = lane; ci < cnt; ci += 64) {
        const float dc = sd2[wave][ci];
        const int   ic = sid[wave][ci];
        int rank = 0;
        for (int j = 0; j < cnt; ++j) {
            const float dj = sd2[wave][j];
            const int   ij = sid[wave][j];
            rank += (dj < dc || (dj == dc && ij < ic)) ? 1 : 0;
        }
        if (rank < KK) nbr[c * KK + rank] = ic;
    }
    if (lane == 0) cntbuf[c] = (cnt < KK) ? cnt : KK;
}

// ---------------- Kernel 3: gather + MLP + max-pool, one wave per center ----
__global__ __launch_bounds__(256) void mlp_kernel(
    const float* __restrict__ x,
    const float* __restrict__ pos,
    const float* __restrict__ W1,
    const float* __restrict__ b1,
    const float* __restrict__ W2,
    const float* __restrict__ b2,
    const int* __restrict__ nbr,
    const int* __restrict__ cntbuf,
    const float* __restrict__ centers,
    float* __restrict__ out)
{
    __shared__ float WT[64 * 68];
    __shared__ float featL[4][32 * 68];

    const int tid = threadIdx.x, wave = tid >> 6, lane = tid & 63;
    const int c = blockIdx.x * 4 + wave;
    const int b = c >> 11;
    const int cnt = cntbuf[c];

    for (int idx = tid; idx < 67 * 64; idx += 256) {
        const int i = idx >> 6, h = idx & 63;
        WT[h * 68 + i] = W1[idx];
    }
    if (tid < 64) WT[tid * 68 + 67] = 0.0f;

    const float ctr0 = centers[c * 3 + 0];
    const float ctr1 = centers[c * 3 + 1];
    const float ctr2 = centers[c * 3 + 2];
    for (int k = 0; k < cnt; ++k) {
        const int j = nbr[c * KK + k];
        featL[wave][k * 68 + lane] = x[((size_t)b * NN + j) * FF + lane];
        if (lane < 3) {
            const float pj = pos[((size_t)b * NN + j) * 3 + lane];
            const float ci = (lane == 0) ? ctr0 : ((lane == 1) ? ctr1 : ctr2);
            featL[wave][k * 68 + 64 + lane] = __fsub_rn(pj, ci);
        }
        if (lane == 3) featL[wave][k * 68 + 67] = 0.0f;
    }
    __syncthreads();

    float wreg[68];
#pragma unroll
    for (int i4 = 0; i4 < 17; ++i4) {
        const float4 v = *(const float4*)&WT[lane * 68 + i4 * 4];
        wreg[i4 * 4 + 0] = v.x; wreg[i4 * 4 + 1] = v.y;
        wreg[i4 * 4 + 2] = v.z; wreg[i4 * 4 + 3] = v.w;
    }
    const float bias1 = b1[lane];
    for (int k = 0; k < cnt; ++k) {
        float acc = bias1;
#pragma unroll
        for (int i4 = 0; i4 < 17; ++i4) {
            const float4 f = *(const float4*)&featL[wave][k * 68 + i4 * 4];
            acc = fmaf(f.x, wreg[i4 * 4 + 0], acc);
            acc = fmaf(f.y, wreg[i4 * 4 + 1], acc);
            acc = fmaf(f.z, wreg[i4 * 4 + 2], acc);
            acc = fmaf(f.w, wreg[i4 * 4 + 3], acc);
        }
        featL[wave][k * 68 + lane] = fmaxf(acc, 0.0f);
    }
    __syncthreads();

    for (int idx = tid; idx < 64 * 64; idx += 256) {
        const int i = idx >> 6, h = idx & 63;
        WT[h * 68 + i] = W2[idx];
    }
    __syncthreads();

#pragma unroll
    for (int i4 = 0; i4 < 16; ++i4) {
        const float4 v = *(const float4*)&WT[lane * 68 + i4 * 4];
        wreg[i4 * 4 + 0] = v.x; wreg[i4 * 4 + 1] = v.y;
        wreg[i4 * 4 + 2] = v.z; wreg[i4 * 4 + 3] = v.w;
    }
    const float bias2 = b2[lane];
    float m = -INFINITY;
    for (int k = 0; k < cnt; ++k) {
        float acc = bias2;
#pragma unroll
        for (int i4 = 0; i4 < 16; ++i4) {
            const float4 f = *(const float4*)&featL[wave][k * 68 + i4 * 4];
            acc = fmaf(f.x, wreg[i4 * 4 + 0], acc);
            acc = fmaf(f.y, wreg[i4 * 4 + 1], acc);
            acc = fmaf(f.z, wreg[i4 * 4 + 2], acc);
            acc = fmaf(f.w, wreg[i4 * 4 + 3], acc);
        }
        m = fmaxf(m, fmaxf(acc, 0.0f));
    }
    out[(size_t)c * HH + lane] = (cnt > 0) ? m : 0.0f;
}

extern "C" void kernel_launch(void* const* d_in, const int* in_sizes, int n_in,
                              void* d_out, int out_size, void* d_ws, size_t ws_size,
                              hipStream_t stream) {
    const float* x   = (const float*)d_in[0];
    const float* pos = (const float*)d_in[1];
    const float* W1  = (const float*)d_in[3];
    const float* b1  = (const float*)d_in[4];
    const float* W2  = (const float*)d_in[5];
    const float* b2  = (const float*)d_in[6];

    float* out         = (float*)d_out;
    float* centers_out = out + (size_t)NB * MM * HH;
    float* batch_out   = centers_out + (size_t)NB * MM * 3;

    char* ws = (char*)d_ws;
    int* samp   = (int*)ws;
    int* cntbuf = (int*)(ws + (size_t)NB * MM * 4);
    int* nbr    = (int*)(ws + (size_t)2 * NB * MM * 4);

    fps_kernel<<<NB, FT, 0, stream>>>(pos, samp, centers_out, batch_out);
    knn_kernel<<<(NB * MM) / 4, 256, 0, stream>>>(pos, samp, nbr, cntbuf);
    mlp_kernel<<<(NB * MM) / 4, 256, 0, stream>>>(x, pos, W1, b1, W2, b2,
                                                  nbr, cntbuf, centers_out, out);
}

// Round 5
// 4728.230 us; speedup vs baseline: 1.6469x; 1.6469x over previous
//
#include <hip/hip_runtime.h>
#include <hip/hip_bf16.h>
#include <float.h>
#include <math.h>

#define NB 4
#define NN 8192
#define FF 64
#define MM 2048
#define KK 32
#define HH 64

#define FT 512          // fps threads (8 waves)
#define PPT 16          // points per thread-bucket (FT*PPT == NN)

// 3-wide DPP argmax step: carries (value, orig idx, lds slot); tie -> lower oi.
// identities: v=-inf, oi=INT_MAX, si=0 (never selected). (verified round 4)
#define DPP3_STEP(bv, boi, bsi, ctrl, rmask)                                    \
    {                                                                           \
        int _v  = __builtin_amdgcn_update_dpp((int)0xff800000,                  \
                      __float_as_int(bv), (ctrl), (rmask), 0xf, false);         \
        int _oi = __builtin_amdgcn_update_dpp((int)0x7fffffff,                  \
                      (boi), (ctrl), (rmask), 0xf, false);                      \
        int _si = __builtin_amdgcn_update_dpp(0, (bsi), (ctrl), (rmask), 0xf, false); \
        float _vf = __int_as_float(_v);                                         \
        if (_vf > (bv) || (_vf == (bv) && _oi < (boi)))                         \
            { (bv) = _vf; (boi) = _oi; (bsi) = _si; }                           \
    }
#define DPP3_REDUCE(bv, boi, bsi)            \
    DPP3_STEP(bv, boi, bsi, 0x111, 0xf)      \
    DPP3_STEP(bv, boi, bsi, 0x112, 0xf)      \
    DPP3_STEP(bv, boi, bsi, 0x114, 0xf)      \
    DPP3_STEP(bv, boi, bsi, 0x118, 0xf)      \
    DPP3_STEP(bv, boi, bsi, 0x142, 0xa)      \
    DPP3_STEP(bv, boi, bsi, 0x143, 0xc)

__device__ __forceinline__ int spread3(int v) {
    return (v & 1) | ((v & 2) << 2) | ((v & 4) << 4);
}

// comparator for (value, oi-bits, si-bits, pad) in float4: max value, tie -> lower oi
__device__ __forceinline__ float4 argmax3(float4 a, float4 b) {
    const int ia = __float_as_int(a.y), ib = __float_as_int(b.y);
    return (b.x > a.x || (b.x == a.x && ib < ia)) ? b : a;
}

// ---------------- Kernel 1: exact FPS, per-thread bucket pruning ----------------
__global__ __launch_bounds__(FT) void fps_kernel(
    const float* __restrict__ pos,
    int* __restrict__ samp,
    float* __restrict__ centers_out,
    float* __restrict__ batch_out)
{
    // transposed point store: pts_t[i*FT + t] = point i of thread t's bucket
    // .xyz = coords (Morton-sorted), .w = original index bits. 128 KB.
    __shared__ float4 pts_t[NN];
    __shared__ float4 slots[2][8];       // parity-buffered per-wave winners
    __shared__ int hist[512], off[512];

    const int b = blockIdx.x;
    const float* pb = pos + (size_t)b * NN * 3;
    const int tid = threadIdx.x;
    const int w   = tid >> 6;

    // ---- setup: load, morton code, counting sort into transposed layout ----
    float px[PPT], py[PPT], pz[PPT];
    int   mt[PPT];
    hist[tid] = 0;
    __syncthreads();
#pragma unroll
    for (int i = 0; i < PPT; ++i) {
        const int j = tid + i * FT;
        px[i] = pb[j * 3 + 0];
        py[i] = pb[j * 3 + 1];
        pz[i] = pb[j * 3 + 2];
        int cx = (int)(px[i] * 8.0f), cy = (int)(py[i] * 8.0f), cz = (int)(pz[i] * 8.0f);
        cx = min(max(cx, 0), 7); cy = min(max(cy, 0), 7); cz = min(max(cz, 0), 7);
        mt[i] = spread3(cx) | (spread3(cy) << 1) | (spread3(cz) << 2);
        atomicAdd(&hist[mt[i]], 1);
    }
    for (int j = tid; j < MM; j += FT) batch_out[b * MM + j] = (float)b;
    __syncthreads();
    for (int d = 1; d < 512; d <<= 1) {
        int v = hist[tid] + ((tid >= d) ? hist[tid - d] : 0);
        __syncthreads();
        hist[tid] = v;
        __syncthreads();
    }
    off[tid] = (tid == 0) ? 0 : hist[tid - 1];
    __syncthreads();
#pragma unroll
    for (int i = 0; i < PPT; ++i) {
        const int slot = atomicAdd(&off[mt[i]], 1);
        // transposed address: point-within-bucket = slot&15, bucket = slot>>4
        pts_t[(slot & 15) * FT + (slot >> 4)] =
            make_float4(px[i], py[i], pz[i], __int_as_float(tid + i * FT));
    }
    __syncthreads();

    // ---- per-thread bucket stats: centroid + conservative radius ----
    float bx[PPT], by[PPT], bz[PPT], dist[PPT];
    float sx = 0.0f, sy = 0.0f, sz = 0.0f;
#pragma unroll
    for (int i = 0; i < PPT; ++i) {
        const float4 p = pts_t[i * FT + tid];
        bx[i] = p.x; by[i] = p.y; bz[i] = p.z;
        sx += p.x; sy += p.y; sz += p.z;
        dist[i] = INFINITY;
    }
    const float gx = sx * (1.0f / PPT), gy = sy * (1.0f / PPT), gz = sz * (1.0f / PPT);
    float r2m = 0.0f;
#pragma unroll
    for (int i = 0; i < PPT; ++i) {
        const float dx = bx[i] - gx, dy = by[i] - gy, dz = bz[i] - gz;
        r2m = fmaxf(r2m, dx * dx + dy * dy + dz * dz);
    }
    const float rad = sqrtf(r2m) * 1.00005f + 1e-7f;

    float bv = INFINITY;          // cached bucket max (inf => never skip yet)
    int   boi = 0x7fffffff, bsi = 0;

    int   cur = 0;
    float lx = pb[0], ly = pb[1], lz = pb[2];

    for (int s = 0; s < MM; ++s) {
        if (tid == 0) {
            samp[b * MM + s] = cur;
            centers_out[((size_t)b * MM + s) * 3 + 0] = lx;
            centers_out[((size_t)b * MM + s) * 3 + 1] = ly;
            centers_out[((size_t)b * MM + s) * 3 + 2] = lz;
        }
        if (s == MM - 1) break;

        // ---- per-thread prune test (margins conservative; dist stays exact) ----
        const float dxc = gx - lx, dyc = gy - ly, dzc = gz - lz;
        const float d2c = dxc * dxc + dyc * dyc + dzc * dzc;
        const float t   = __fsub_rn(__fmul_rn(sqrtf(d2c), 0.99999f), rad);
        const bool skip = (t > 0.0f) &&
                          (__fmul_rn(t, t) >= __fmul_rn(bv, 1.00004f));

        if (!skip) {
            float nbv = -INFINITY; int nboi = 0x7fffffff, nbsi = 0;
#pragma unroll
            for (int i = 0; i < PPT; ++i) {
                // exact ref arithmetic: ((dx*dx + dy*dy) + dz*dz), no FMA
                const float dx = __fsub_rn(bx[i], lx);
                const float dy = __fsub_rn(by[i], ly);
                const float dz = __fsub_rn(bz[i], lz);
                const float d  = __fadd_rn(__fadd_rn(__fmul_rn(dx, dx),
                                                     __fmul_rn(dy, dy)),
                                           __fmul_rn(dz, dz));
                const float nd = fminf(dist[i], d);
                dist[i] = nd;
                const int oi = __float_as_int(pts_t[i * FT + tid].w);
                if (nd > nbv || (nd == nbv && oi < nboi)) {
                    nbv = nd; nboi = oi; nbsi = i * FT + tid;
                }
            }
            bv = nbv; boi = nboi; bsi = nbsi;
        }

        // ---- single wave DPP3 argmax on cached values (copies!) ----
        float wv = bv; int woi = boi, wsi = bsi;
        DPP3_REDUCE(wv, woi, wsi)
        const int par = s & 1;
        if ((tid & 63) == 63)
            slots[par][w] = make_float4(wv, __int_as_float(woi),
                                        __int_as_float(wsi), 0.0f);
        __syncthreads();

        // ---- scan 8 per-wave winners (broadcast reads, comparator tree) ----
        const float4 s0 = slots[par][0], s1 = slots[par][1];
        const float4 s2 = slots[par][2], s3 = slots[par][3];
        const float4 s4 = slots[par][4], s5 = slots[par][5];
        const float4 s6 = slots[par][6], s7 = slots[par][7];
        const float4 a0 = argmax3(s0, s1), a1 = argmax3(s2, s3);
        const float4 a2 = argmax3(s4, s5), a3 = argmax3(s6, s7);
        const float4 b0 = argmax3(a0, a1), b1 = argmax3(a2, a3);
        const float4 win = argmax3(b0, b1);

        cur = __float_as_int(win.y);
        const float4 wp = pts_t[__float_as_int(win.z)];
        lx = wp.x; ly = wp.y; lz = wp.z;
    }
}

// ---------------- Kernel 2: radius-KNN, one wave per center ----------------
#define CAP 256
__global__ __launch_bounds__(256) void knn_kernel(
    const float* __restrict__ pos,
    const int* __restrict__ samp,
    int* __restrict__ nbr,
    int* __restrict__ cntbuf)
{
    const int wave = threadIdx.x >> 6;
    const int lane = threadIdx.x & 63;
    const int c = blockIdx.x * 4 + wave;
    const int b = c >> 11;
    const float* pb = pos + (size_t)b * NN * 3;

    __shared__ float sd2[4][CAP];
    __shared__ int   sid[4][CAP];

    const int ctr = samp[c];
    const float cx = pb[ctr * 3 + 0];
    const float cy = pb[ctr * 3 + 1];
    const float cz = pb[ctr * 3 + 2];
    const float R2 = (float)(0.1 * 0.1);

    int cnt = 0;
    for (int r = 0; r < NN / 64; ++r) {
        const int g = r * 64 + lane;
        float dx = __fsub_rn(cx, pb[g * 3 + 0]);
        float dy = __fsub_rn(cy, pb[g * 3 + 1]);
        float dz = __fsub_rn(cz, pb[g * 3 + 2]);
        float d2 = __fadd_rn(__fadd_rn(__fmul_rn(dx, dx), __fmul_rn(dy, dy)),
                             __fmul_rn(dz, dz));
        const bool pred = (d2 <= R2);
        const unsigned long long mask = __ballot(pred);
        const int before = __popcll(mask & ((1ull << lane) - 1ull));
        if (pred) {
            const int slot = cnt + before;
            if (slot < CAP) { sd2[wave][slot] = d2; sid[wave][slot] = g; }
        }
        cnt += __popcll(mask);
    }
    if (cnt > CAP) cnt = CAP;
    __syncthreads();

    for (int ci = lane; ci < cnt; ci += 64) {
        const float dc = sd2[wave][ci];
        const int   ic = sid[wave][ci];
        int rank = 0;
        for (int j = 0; j < cnt; ++j) {
            const float dj = sd2[wave][j];
            const int   ij = sid[wave][j];
            rank += (dj < dc || (dj == dc && ij < ic)) ? 1 : 0;
        }
        if (rank < KK) nbr[c * KK + rank] = ic;
    }
    if (lane == 0) cntbuf[c] = (cnt < KK) ? cnt : KK;
}

// ---------------- Kernel 3: gather + MLP + max-pool, one wave per center ----
__global__ __launch_bounds__(256) void mlp_kernel(
    const float* __restrict__ x,
    const float* __restrict__ pos,
    const float* __restrict__ W1,
    const float* __restrict__ b1,
    const float* __restrict__ W2,
    const float* __restrict__ b2,
    const int* __restrict__ nbr,
    const int* __restrict__ cntbuf,
    const float* __restrict__ centers,
    float* __restrict__ out)
{
    __shared__ float WT[64 * 68];
    __shared__ float featL[4][32 * 68];

    const int tid = threadIdx.x, wave = tid >> 6, lane = tid & 63;
    const int c = blockIdx.x * 4 + wave;
    const int b = c >> 11;
    const int cnt = cntbuf[c];

    for (int idx = tid; idx < 67 * 64; idx += 256) {
        const int i = idx >> 6, h = idx & 63;
        WT[h * 68 + i] = W1[idx];
    }
    if (tid < 64) WT[tid * 68 + 67] = 0.0f;

    const float ctr0 = centers[c * 3 + 0];
    const float ctr1 = centers[c * 3 + 1];
    const float ctr2 = centers[c * 3 + 2];
    for (int k = 0; k < cnt; ++k) {
        const int j = nbr[c * KK + k];
        featL[wave][k * 68 + lane] = x[((size_t)b * NN + j) * FF + lane];
        if (lane < 3) {
            const float pj = pos[((size_t)b * NN + j) * 3 + lane];
            const float ci = (lane == 0) ? ctr0 : ((lane == 1) ? ctr1 : ctr2);
            featL[wave][k * 68 + 64 + lane] = __fsub_rn(pj, ci);
        }
        if (lane == 3) featL[wave][k * 68 + 67] = 0.0f;
    }
    __syncthreads();

    float wreg[68];
#pragma unroll
    for (int i4 = 0; i4 < 17; ++i4) {
        const float4 v = *(const float4*)&WT[lane * 68 + i4 * 4];
        wreg[i4 * 4 + 0] = v.x; wreg[i4 * 4 + 1] = v.y;
        wreg[i4 * 4 + 2] = v.z; wreg[i4 * 4 + 3] = v.w;
    }
    const float bias1 = b1[lane];
    for (int k = 0; k < cnt; ++k) {
        float acc = bias1;
#pragma unroll
        for (int i4 = 0; i4 < 17; ++i4) {
            const float4 f = *(const float4*)&featL[wave][k * 68 + i4 * 4];
            acc = fmaf(f.x, wreg[i4 * 4 + 0], acc);
            acc = fmaf(f.y, wreg[i4 * 4 + 1], acc);
            acc = fmaf(f.z, wreg[i4 * 4 + 2], acc);
            acc = fmaf(f.w, wreg[i4 * 4 + 3], acc);
        }
        featL[wave][k * 68 + lane] = fmaxf(acc, 0.0f);
    }
    __syncthreads();

    for (int idx = tid; idx < 64 * 64; idx += 256) {
        const int i = idx >> 6, h = idx & 63;
        WT[h * 68 + i] = W2[idx];
    }
    __syncthreads();

#pragma unroll
    for (int i4 = 0; i4 < 16; ++i4) {
        const float4 v = *(const float4*)&WT[lane * 68 + i4 * 4];
        wreg[i4 * 4 + 0] = v.x; wreg[i4 * 4 + 1] = v.y;
        wreg[i4 * 4 + 2] = v.z; wreg[i4 * 4 + 3] = v.w;
    }
    const float bias2 = b2[lane];
    float m = -INFINITY;
    for (int k = 0; k < cnt; ++k) {
        float acc = bias2;
#pragma unroll
        for (int i4 = 0; i4 < 16; ++i4) {
            const float4 f = *(const float4*)&featL[wave][k * 68 + i4 * 4];
            acc = fmaf(f.x, wreg[i4 * 4 + 0], acc);
            acc = fmaf(f.y, wreg[i4 * 4 + 1], acc);
            acc = fmaf(f.z, wreg[i4 * 4 + 2], acc);
            acc = fmaf(f.w, wreg[i4 * 4 + 3], acc);
        }
        m = fmaxf(m, fmaxf(acc, 0.0f));
    }
    out[(size_t)c * HH + lane] = (cnt > 0) ? m : 0.0f;
}

extern "C" void kernel_launch(void* const* d_in, const int* in_sizes, int n_in,
                              void* d_out, int out_size, void* d_ws, size_t ws_size,
                              hipStream_t stream) {
    const float* x   = (const float*)d_in[0];
    const float* pos = (const float*)d_in[1];
    const float* W1  = (const float*)d_in[3];
    const float* b1  = (const float*)d_in[4];
    const float* W2  = (const float*)d_in[5];
    const float* b2  = (const float*)d_in[6];

    float* out         = (float*)d_out;
    float* centers_out = out + (size_t)NB * MM * HH;
    float* batch_out   = centers_out + (size_t)NB * MM * 3;

    char* ws = (char*)d_ws;
    int* samp   = (int*)ws;
    int* cntbuf = (int*)(ws + (size_t)NB * MM * 4);
    int* nbr    = (int*)(ws + (size_t)2 * NB * MM * 4);

    fps_kernel<<<NB, FT, 0, stream>>>(pos, samp, centers_out, batch_out);
    knn_kernel<<<(NB * MM) / 4, 256, 0, stream>>>(pos, samp, nbr, cntbuf);
    mlp_kernel<<<(NB * MM) / 4, 256, 0, stream>>>(x, pos, W1, b1, W2, b2,
                                                  nbr, cntbuf, centers_out, out);
}

// Round 6
// 4142.186 us; speedup vs baseline: 1.8799x; 1.1415x over previous
//
#include <hip/hip_runtime.h>
#include <hip/hip_bf16.h>
#include <float.h>
#include <math.h>

#define NB 4
#define NN 8192
#define FF 64
#define MM 2048
#define KK 32
#define HH 64

#define FT 512          // fps threads (8 waves)
#define PPT 16          // points per thread-bucket (FT*PPT == NN)

// 3-wide DPP argmax step: carries (value, orig idx, lds slot); tie -> lower oi.
// identities: v=-inf, oi=INT_MAX, si=0 (never selected). (verified r4/r5)
#define DPP3_STEP(bv, boi, bsi, ctrl, rmask)                                    \
    {                                                                           \
        int _v  = __builtin_amdgcn_update_dpp((int)0xff800000,                  \
                      __float_as_int(bv), (ctrl), (rmask), 0xf, false);         \
        int _oi = __builtin_amdgcn_update_dpp((int)0x7fffffff,                  \
                      (boi), (ctrl), (rmask), 0xf, false);                      \
        int _si = __builtin_amdgcn_update_dpp(0, (bsi), (ctrl), (rmask), 0xf, false); \
        float _vf = __int_as_float(_v);                                         \
        if (_vf > (bv) || (_vf == (bv) && _oi < (boi)))                         \
            { (bv) = _vf; (boi) = _oi; (bsi) = _si; }                           \
    }
#define DPP3_REDUCE(bv, boi, bsi)            \
    DPP3_STEP(bv, boi, bsi, 0x111, 0xf)      \
    DPP3_STEP(bv, boi, bsi, 0x112, 0xf)      \
    DPP3_STEP(bv, boi, bsi, 0x114, 0xf)      \
    DPP3_STEP(bv, boi, bsi, 0x118, 0xf)      \
    DPP3_STEP(bv, boi, bsi, 0x142, 0xa)      \
    DPP3_STEP(bv, boi, bsi, 0x143, 0xc)

__device__ __forceinline__ int spread3(int v) {
    return (v & 1) | ((v & 2) << 2) | ((v & 4) << 4);
}

// comparator for (value, oi-bits, si-bits, pad) in float4: max value, tie -> lower oi
__device__ __forceinline__ float4 argmax3(float4 a, float4 b) {
    const int ia = __float_as_int(a.y), ib = __float_as_int(b.y);
    return (b.x > a.x || (b.x == a.x && ib < ia)) ? b : a;
}

// ---------------- Kernel 1: exact FPS, register-resident buckets ----------------
__global__ __launch_bounds__(FT) void fps_kernel(
    const float* __restrict__ pos,
    int* __restrict__ samp,
    float* __restrict__ centers_out,
    float* __restrict__ batch_out)
{
    // sorted point store, only used for (a) one-time register fill,
    // (b) per-step winner coordinate fetch (broadcast -> conflict-free).
    __shared__ float4 pts4[NN];          // .xyz coords, .w = orig idx bits (128 KB)
    __shared__ float4 slots[2][8];       // parity-buffered per-wave winners
    __shared__ int hist[512], off[512];

    const int b = blockIdx.x;
    const float* pb = pos + (size_t)b * NN * 3;
    const int tid = threadIdx.x;
    const int w   = tid >> 6;

    // ---- setup: load, morton code, counting sort (one-time cost) ----
    float px[PPT], py[PPT], pz[PPT];
    int   mt[PPT];
    hist[tid] = 0;
    __syncthreads();
#pragma unroll
    for (int i = 0; i < PPT; ++i) {
        const int j = tid + i * FT;
        px[i] = pb[j * 3 + 0];
        py[i] = pb[j * 3 + 1];
        pz[i] = pb[j * 3 + 2];
        int cx = (int)(px[i] * 8.0f), cy = (int)(py[i] * 8.0f), cz = (int)(pz[i] * 8.0f);
        cx = min(max(cx, 0), 7); cy = min(max(cy, 0), 7); cz = min(max(cz, 0), 7);
        mt[i] = spread3(cx) | (spread3(cy) << 1) | (spread3(cz) << 2);
        atomicAdd(&hist[mt[i]], 1);
    }
    for (int j = tid; j < MM; j += FT) batch_out[b * MM + j] = (float)b;
    __syncthreads();
    for (int d = 1; d < 512; d <<= 1) {
        int v = hist[tid] + ((tid >= d) ? hist[tid - d] : 0);
        __syncthreads();
        hist[tid] = v;
        __syncthreads();
    }
    off[tid] = (tid == 0) ? 0 : hist[tid - 1];
    __syncthreads();
#pragma unroll
    for (int i = 0; i < PPT; ++i) {
        const int slot = atomicAdd(&off[mt[i]], 1);
        // thread t's bucket = sorted slots [t*16, t*16+16): transposed address
        pts4[(slot & 15) * FT + (slot >> 4)] =
            make_float4(px[i], py[i], pz[i], __int_as_float(tid + i * FT));
    }
    __syncthreads();

    // ---- register fill: this thread's 16 bucket points + orig indices ----
    float dist[PPT];
    int   oi_r[PPT];
    float sx = 0.0f, sy = 0.0f, sz = 0.0f;
#pragma unroll
    for (int i = 0; i < PPT; ++i) {
        const float4 p = pts4[i * FT + tid];
        px[i] = p.x; py[i] = p.y; pz[i] = p.z;
        oi_r[i] = __float_as_int(p.w);
        sx += p.x; sy += p.y; sz += p.z;
        dist[i] = INFINITY;
    }
    const float gx = sx * (1.0f / PPT), gy = sy * (1.0f / PPT), gz = sz * (1.0f / PPT);
    float r2m = 0.0f;
#pragma unroll
    for (int i = 0; i < PPT; ++i) {
        const float dx = px[i] - gx, dy = py[i] - gy, dz = pz[i] - gz;
        r2m = fmaxf(r2m, dx * dx + dy * dy + dz * dz);
    }
    const float rad = sqrtf(r2m) * 1.00005f + 1e-7f;   // conservative upper bound

    float bv = INFINITY;          // cached bucket max (inf => never skip yet)
    int   boi = 0x7fffffff, bsi = 0;

    int   cur = 0;
    float lx = pb[0], ly = pb[1], lz = pb[2];

    for (int s = 0; s < MM; ++s) {
        if (tid == 0) {
            samp[b * MM + s] = cur;
            centers_out[((size_t)b * MM + s) * 3 + 0] = lx;
            centers_out[((size_t)b * MM + s) * 3 + 1] = ly;
            centers_out[((size_t)b * MM + s) * 3 + 2] = lz;
        }
        if (s == MM - 1) break;

        // ---- per-thread prune test (conservative margins; dist stays exact) ----
        const float dxc = gx - lx, dyc = gy - ly, dzc = gz - lz;
        const float d2c = dxc * dxc + dyc * dyc + dzc * dzc;
        const float t   = __fsub_rn(__fmul_rn(sqrtf(d2c), 0.99999f), rad);
        const bool skip = (t > 0.0f) &&
                          (__fmul_rn(t, t) >= __fmul_rn(bv, 1.00004f));

        if (!skip) {
            // pure-register update: no LDS access anywhere in this loop
            float nbv = -INFINITY; int nboi = 0x7fffffff, nbsi = 0;
#pragma unroll
            for (int i = 0; i < PPT; ++i) {
                // exact ref arithmetic: ((dx*dx + dy*dy) + dz*dz), no FMA
                const float dx = __fsub_rn(px[i], lx);
                const float dy = __fsub_rn(py[i], ly);
                const float dz = __fsub_rn(pz[i], lz);
                const float d  = __fadd_rn(__fadd_rn(__fmul_rn(dx, dx),
                                                     __fmul_rn(dy, dy)),
                                           __fmul_rn(dz, dz));
                const float nd = fminf(dist[i], d);
                dist[i] = nd;
                if (nd > nbv || (nd == nbv && oi_r[i] < nboi)) {
                    nbv = nd; nboi = oi_r[i]; nbsi = i * FT + tid;
                }
            }
            bv = nbv; boi = nboi; bsi = nbsi;
        }

        // ---- single wave DPP3 argmax on cached values (copies!) ----
        float wv = bv; int woi = boi, wsi = bsi;
        DPP3_REDUCE(wv, woi, wsi)
        const int par = s & 1;
        if ((tid & 63) == 63)
            slots[par][w] = make_float4(wv, __int_as_float(woi),
                                        __int_as_float(wsi), 0.0f);
        __syncthreads();

        // ---- scan 8 per-wave winners (broadcast reads, comparator tree) ----
        const float4 s0 = slots[par][0], s1 = slots[par][1];
        const float4 s2 = slots[par][2], s3 = slots[par][3];
        const float4 s4 = slots[par][4], s5 = slots[par][5];
        const float4 s6 = slots[par][6], s7 = slots[par][7];
        const float4 a0 = argmax3(s0, s1), a1 = argmax3(s2, s3);
        const float4 a2 = argmax3(s4, s5), a3 = argmax3(s6, s7);
        const float4 b0 = argmax3(a0, a1), b1 = argmax3(a2, a3);
        const float4 win = argmax3(b0, b1);

        cur = __float_as_int(win.y);
        const float4 wp = pts4[__float_as_int(win.z)];   // broadcast, conflict-free
        lx = wp.x; ly = wp.y; lz = wp.z;
    }
}

// ---------------- Kernel 2: radius-KNN, one wave per center ----------------
#define CAP 256
__global__ __launch_bounds__(256) void knn_kernel(
    const float* __restrict__ pos,
    const int* __restrict__ samp,
    int* __restrict__ nbr,
    int* __restrict__ cntbuf)
{
    const int wave = threadIdx.x >> 6;
    const int lane = threadIdx.x & 63;
    const int c = blockIdx.x * 4 + wave;
    const int b = c >> 11;
    const float* pb = pos + (size_t)b * NN * 3;

    __shared__ float sd2[4][CAP];
    __shared__ int   sid[4][CAP];

    const int ctr = samp[c];
    const float cx = pb[ctr * 3 + 0];
    const float cy = pb[ctr * 3 + 1];
    const float cz = pb[ctr * 3 + 2];
    const float R2 = (float)(0.1 * 0.1);

    int cnt = 0;
    for (int r = 0; r < NN / 64; ++r) {
        const int g = r * 64 + lane;
        float dx = __fsub_rn(cx, pb[g * 3 + 0]);
        float dy = __fsub_rn(cy, pb[g * 3 + 1]);
        float dz = __fsub_rn(cz, pb[g * 3 + 2]);
        float d2 = __fadd_rn(__fadd_rn(__fmul_rn(dx, dx), __fmul_rn(dy, dy)),
                             __fmul_rn(dz, dz));
        const bool pred = (d2 <= R2);
        const unsigned long long mask = __ballot(pred);
        const int before = __popcll(mask & ((1ull << lane) - 1ull));
        if (pred) {
            const int slot = cnt + before;
            if (slot < CAP) { sd2[wave][slot] = d2; sid[wave][slot] = g; }
        }
        cnt += __popcll(mask);
    }
    if (cnt > CAP) cnt = CAP;
    __syncthreads();

    for (int ci = lane; ci < cnt; ci += 64) {
        const float dc = sd2[wave][ci];
        const int   ic = sid[wave][ci];
        int rank = 0;
        for (int j = 0; j < cnt; ++j) {
            const float dj = sd2[wave][j];
            const int   ij = sid[wave][j];
            rank += (dj < dc || (dj == dc && ij < ic)) ? 1 : 0;
        }
        if (rank < KK) nbr[c * KK + rank] = ic;
    }
    if (lane == 0) cntbuf[c] = (cnt < KK) ? cnt : KK;
}

// ---------------- Kernel 3: gather + MLP + max-pool, one wave per center ----
__global__ __launch_bounds__(256) void mlp_kernel(
    const float* __restrict__ x,
    const float* __restrict__ pos,
    const float* __restrict__ W1,
    const float* __restrict__ b1,
    const float* __restrict__ W2,
    const float* __restrict__ b2,
    const int* __restrict__ nbr,
    const int* __restrict__ cntbuf,
    const float* __restrict__ centers,
    float* __restrict__ out)
{
    __shared__ float WT[64 * 68];
    __shared__ float featL[4][32 * 68];

    const int tid = threadIdx.x, wave = tid >> 6, lane = tid & 63;
    const int c = blockIdx.x * 4 + wave;
    const int b = c >> 11;
    const int cnt = cntbuf[c];

    for (int idx = tid; idx < 67 * 64; idx += 256) {
        const int i = idx >> 6, h = idx & 63;
        WT[h * 68 + i] = W1[idx];
    }
    if (tid < 64) WT[tid * 68 + 67] = 0.0f;

    const float ctr0 = centers[c * 3 + 0];
    const float ctr1 = centers[c * 3 + 1];
    const float ctr2 = centers[c * 3 + 2];
    for (int k = 0; k < cnt; ++k) {
        const int j = nbr[c * KK + k];
        featL[wave][k * 68 + lane] = x[((size_t)b * NN + j) * FF + lane];
        if (lane < 3) {
            const float pj = pos[((size_t)b * NN + j) * 3 + lane];
            const float ci = (lane == 0) ? ctr0 : ((lane == 1) ? ctr1 : ctr2);
            featL[wave][k * 68 + 64 + lane] = __fsub_rn(pj, ci);
        }
        if (lane == 3) featL[wave][k * 68 + 67] = 0.0f;
    }
    __syncthreads();

    float wreg[68];
#pragma unroll
    for (int i4 = 0; i4 < 17; ++i4) {
        const float4 v = *(const float4*)&WT[lane * 68 + i4 * 4];
        wreg[i4 * 4 + 0] = v.x; wreg[i4 * 4 + 1] = v.y;
        wreg[i4 * 4 + 2] = v.z; wreg[i4 * 4 + 3] = v.w;
    }
    const float bias1 = b1[lane];
    for (int k = 0; k < cnt; ++k) {
        float acc = bias1;
#pragma unroll
        for (int i4 = 0; i4 < 17; ++i4) {
            const float4 f = *(const float4*)&featL[wave][k * 68 + i4 * 4];
            acc = fmaf(f.x, wreg[i4 * 4 + 0], acc);
            acc = fmaf(f.y, wreg[i4 * 4 + 1], acc);
            acc = fmaf(f.z, wreg[i4 * 4 + 2], acc);
            acc = fmaf(f.w, wreg[i4 * 4 + 3], acc);
        }
        featL[wave][k * 68 + lane] = fmaxf(acc, 0.0f);
    }
    __syncthreads();

    for (int idx = tid; idx < 64 * 64; idx += 256) {
        const int i = idx >> 6, h = idx & 63;
        WT[h * 68 + i] = W2[idx];
    }
    __syncthreads();

#pragma unroll
    for (int i4 = 0; i4 < 16; ++i4) {
        const float4 v = *(const float4*)&WT[lane * 68 + i4 * 4];
        wreg[i4 * 4 + 0] = v.x; wreg[i4 * 4 + 1] = v.y;
        wreg[i4 * 4 + 2] = v.z; wreg[i4 * 4 + 3] = v.w;
    }
    const float bias2 = b2[lane];
    float m = -INFINITY;
    for (int k = 0; k < cnt; ++k) {
        float acc = bias2;
#pragma unroll
        for (int i4 = 0; i4 < 16; ++i4) {
            const float4 f = *(const float4*)&featL[wave][k * 68 + i4 * 4];
            acc = fmaf(f.x, wreg[i4 * 4 + 0], acc);
            acc = fmaf(f.y, wreg[i4 * 4 + 1], acc);
            acc = fmaf(f.z, wreg[i4 * 4 + 2], acc);
            acc = fmaf(f.w, wreg[i4 * 4 + 3], acc);
        }
        m = fmaxf(m, fmaxf(acc, 0.0f));
    }
    out[(size_t)c * HH + lane] = (cnt > 0) ? m : 0.0f;
}

extern "C" void kernel_launch(void* const* d_in, const int* in_sizes, int n_in,
                              void* d_out, int out_size, void* d_ws, size_t ws_size,
                              hipStream_t stream) {
    const float* x   = (const float*)d_in[0];
    const float* pos = (const float*)d_in[1];
    const float* W1  = (const float*)d_in[3];
    const float* b1  = (const float*)d_in[4];
    const float* W2  = (const float*)d_in[5];
    const float* b2  = (const float*)d_in[6];

    float* out         = (float*)d_out;
    float* centers_out = out + (size_t)NB * MM * HH;
    float* batch_out   = centers_out + (size_t)NB * MM * 3;

    char* ws = (char*)d_ws;
    int* samp   = (int*)ws;
    int* cntbuf = (int*)(ws + (size_t)NB * MM * 4);
    int* nbr    = (int*)(ws + (size_t)2 * NB * MM * 4);

    fps_kernel<<<NB, FT, 0, stream>>>(pos, samp, centers_out, batch_out);
    knn_kernel<<<(NB * MM) / 4, 256, 0, stream>>>(pos, samp, nbr, cntbuf);
    mlp_kernel<<<(NB * MM) / 4, 256, 0, stream>>>(x, pos, W1, b1, W2, b2,
                                                  nbr, cntbuf, centers_out, out);
}